// Round 1
// baseline (525.054 us; speedup 1.0000x reference)
//
#include <hip/hip_runtime.h>
#include <cstdint>
#include <cstddef>

typedef __attribute__((ext_vector_type(8))) short short8;   // 8 x bf16 (4 VGPRs) MFMA frag
typedef __attribute__((ext_vector_type(4))) float f32x4;    // MFMA accumulator
typedef __attribute__((ext_vector_type(4))) unsigned short u16x4;
typedef unsigned short u16;

#define FP_  2048
#define AD_  1024
#define BB_  512
#define TT_  50000
#define BETA_ 0.125f

// ---------- fp32 -> bf16 (RNE) helpers ----------
__device__ __forceinline__ u16 f2bf(float x){
  uint32_t u = __builtin_bit_cast(uint32_t, x);
  u = (u + 0x7fffu + ((u >> 16) & 1u)) >> 16;
  return (u16)u;
}
__device__ __forceinline__ float bf2f(u16 h){
  uint32_t u = ((uint32_t)h) << 16;
  return __builtin_bit_cast(float, u);
}

// ---------- elementwise fp32 -> (hi,lo) bf16 ----------
__global__ void conv_hilo_k(const float* __restrict__ src, u16* __restrict__ hi,
                            u16* __restrict__ lo, int n){
  int i = (blockIdx.x * blockDim.x + threadIdx.x) * 4;
  if (i >= n) return;
  f32x4 v = *reinterpret_cast<const f32x4*>(src + i);
  u16x4 h, l;
  #pragma unroll
  for (int e = 0; e < 4; ++e){
    float x = v[e];
    u16 hs = f2bf(x);
    h[e] = hs;
    l[e] = f2bf(x - bf2f(hs));
  }
  *reinterpret_cast<u16x4*>(hi + i) = h;
  *reinterpret_cast<u16x4*>(lo + i) = l;
}

// ---------- W[R][C] -> out[C][R] with hi/lo split (LDS tile transpose) ----------
__global__ void conv_hilo_T_k(const float* __restrict__ W, u16* __restrict__ hiT,
                              u16* __restrict__ loT, int R, int C){
  __shared__ float tile[32][33];
  int c0 = blockIdx.x * 32;
  int r0 = blockIdx.y * 32;
  int tx = threadIdx.x;   // 0..31
  int ty = threadIdx.y;   // 0..7
  #pragma unroll
  for (int i = 0; i < 32; i += 8)
    tile[ty + i][tx] = W[(size_t)(r0 + ty + i) * C + c0 + tx];
  __syncthreads();
  #pragma unroll
  for (int i = 0; i < 32; i += 8){
    float x = tile[tx][ty + i];              // = W[r0+tx][c0+ty+i]
    u16 hs = f2bf(x);
    size_t o = (size_t)(c0 + ty + i) * R + r0 + tx;   // out[f][a]
    hiT[o] = hs;
    loT[o] = f2bf(x - bf2f(hs));
  }
}

// ---------- c[b] = dot(Xi[b,:], b_temp) : one wave per row ----------
__global__ void dot_rows_k(const float* __restrict__ Xi, const float* __restrict__ bt,
                           float* __restrict__ c, int K){
  int row  = blockIdx.x * 4 + (threadIdx.x >> 6);
  int lane = threadIdx.x & 63;
  float s = 0.f;
  for (int a = lane; a < K; a += 64) s += Xi[(size_t)row * K + a] * bt[a];
  #pragma unroll
  for (int off = 32; off; off >>= 1) s += __shfl_down(s, off);
  if (lane == 0) c[row] = s;
}

// ---------- split-bf16 GEMM: C = alpha*(A·B^T + colBias + rowAdd) ----------
// A given as (Ahi,Alo) bf16 [M][K]. B either (Bhi,Blo) bf16 [N][K], or fp32 [N][K]
// converted to hi/lo during staging (BF32=true).
// a·b approximated by ah·bh + ah·bl + al·bh (3 MFMAs), fp32 accumulate.
template<int TM, int TN, int FM, int FN, bool BF32>
__global__ __launch_bounds__(256, 2)
void gemm_hilo(const u16* __restrict__ Ahi, const u16* __restrict__ Alo,
               const u16* __restrict__ Bhi, const u16* __restrict__ Blo,
               const float* __restrict__ Bf,
               int M, int N, int K,
               float* __restrict__ Cf, u16* __restrict__ Chi, u16* __restrict__ Clo,
               const float* __restrict__ colBias, const float* __restrict__ rowAdd,
               float alpha)
{
  constexpr int BK = 32;
  constexpr int WM = TM / (16 * FM);
  constexpr int WN = TN / (16 * FN);
  static_assert(WM * WN == 4, "4 waves / 256 threads");

  __shared__ u16 lds[(2 * TM + 2 * TN) * BK];
  u16* As_hi = lds;
  u16* As_lo = lds + TM * BK;
  u16* Bs_hi = lds + 2 * TM * BK;
  u16* Bs_lo = lds + 2 * TM * BK + TN * BK;

  const int tid  = threadIdx.x;
  const int m0   = blockIdx.x * TM;
  const int n0   = blockIdx.y * TN;
  const int w    = tid >> 6;
  const int lane = tid & 63;
  const int lr   = lane & 15;   // fragment row index (input row of A / row of B^T)
  const int lg   = lane >> 4;   // k-chunk 0..3 (8 bf16 each)
  const int wm   = w / WN;
  const int wn   = w % WN;

  f32x4 acc[FM][FN];
  #pragma unroll
  for (int i = 0; i < FM; ++i)
    #pragma unroll
    for (int j = 0; j < FN; ++j)
      acc[i][j] = (f32x4){0.f, 0.f, 0.f, 0.f};

  for (int k0 = 0; k0 < K; k0 += BK){
    // ---- stage A (hi & lo), 16B-chunk XOR swizzle: chunk' = chunk ^ ((row>>1)&3) ----
    {
      const int rr = tid >> 2;        // 0..63
      const int ch = tid & 3;         // 16B chunk within 64B row
      #pragma unroll
      for (int p = 0; p < TM / 64; ++p){
        int row = rr + p * 64;
        int gm  = m0 + row;
        int sw  = (ch ^ ((row >> 1) & 3)) << 3;
        short8 vh = *reinterpret_cast<const short8*>(Ahi + (size_t)gm * K + k0 + ch * 8);
        short8 vl = *reinterpret_cast<const short8*>(Alo + (size_t)gm * K + k0 + ch * 8);
        *reinterpret_cast<short8*>(As_hi + row * BK + sw) = vh;
        *reinterpret_cast<short8*>(As_lo + row * BK + sw) = vl;
      }
    }
    // ---- stage B ----
    if constexpr (BF32){
      const int rr = tid >> 3;        // 0..31
      const int c4 = tid & 7;         // 4-float chunk within 128B fp32 row
      #pragma unroll
      for (int p = 0; p < TN / 32; ++p){
        int row = rr + p * 32;
        int gn  = n0 + row; if (gn > N - 1) gn = N - 1;   // clamp: edge tiles read valid junk
        f32x4 v = *reinterpret_cast<const f32x4*>(Bf + (size_t)gn * K + k0 + c4 * 4);
        u16x4 h, l;
        #pragma unroll
        for (int e = 0; e < 4; ++e){
          float x = v[e];
          u16 hs = f2bf(x);
          h[e] = hs;
          l[e] = f2bf(x - bf2f(hs));
        }
        int off = row * BK + (((c4 >> 1) ^ ((row >> 1) & 3)) << 3) + (c4 & 1) * 4;
        *reinterpret_cast<u16x4*>(Bs_hi + off) = h;
        *reinterpret_cast<u16x4*>(Bs_lo + off) = l;
      }
    } else {
      const int rr = tid >> 2;
      const int ch = tid & 3;
      #pragma unroll
      for (int p = 0; p < TN / 64; ++p){
        int row = rr + p * 64;
        int gn  = n0 + row; if (gn > N - 1) gn = N - 1;
        int sw  = (ch ^ ((row >> 1) & 3)) << 3;
        short8 vh = *reinterpret_cast<const short8*>(Bhi + (size_t)gn * K + k0 + ch * 8);
        short8 vl = *reinterpret_cast<const short8*>(Blo + (size_t)gn * K + k0 + ch * 8);
        *reinterpret_cast<short8*>(Bs_hi + row * BK + sw) = vh;
        *reinterpret_cast<short8*>(Bs_lo + row * BK + sw) = vl;
      }
    }
    __syncthreads();

    // ---- fragments + MFMA ----
    short8 ah[FM], al[FM], bh[FN], bl[FN];
    #pragma unroll
    for (int i = 0; i < FM; ++i){
      int row = wm * FM * 16 + i * 16 + lr;
      int off = row * BK + ((lg ^ ((row >> 1) & 3)) << 3);
      ah[i] = *reinterpret_cast<short8*>(As_hi + off);
      al[i] = *reinterpret_cast<short8*>(As_lo + off);
    }
    #pragma unroll
    for (int j = 0; j < FN; ++j){
      int row = wn * FN * 16 + j * 16 + lr;
      int off = row * BK + ((lg ^ ((row >> 1) & 3)) << 3);
      bh[j] = *reinterpret_cast<short8*>(Bs_hi + off);
      bl[j] = *reinterpret_cast<short8*>(Bs_lo + off);
    }
    #pragma unroll
    for (int i = 0; i < FM; ++i)
      #pragma unroll
      for (int j = 0; j < FN; ++j){
        acc[i][j] = __builtin_amdgcn_mfma_f32_16x16x32_bf16(ah[i], bh[j], acc[i][j], 0, 0, 0);
        acc[i][j] = __builtin_amdgcn_mfma_f32_16x16x32_bf16(ah[i], bl[j], acc[i][j], 0, 0, 0);
        acc[i][j] = __builtin_amdgcn_mfma_f32_16x16x32_bf16(al[i], bh[j], acc[i][j], 0, 0, 0);
      }
    __syncthreads();
  }

  // ---- epilogue: C[row= A index][col= B index]; row=(lane>>4)*4+reg, col=lane&15 ----
  #pragma unroll
  for (int i = 0; i < FM; ++i){
    int rbase = m0 + wm * FM * 16 + i * 16 + lg * 4;
    #pragma unroll
    for (int j = 0; j < FN; ++j){
      int gcol = n0 + wn * FN * 16 + j * 16 + lr;
      if (gcol < N){
        float cb = colBias ? colBias[gcol] : 0.f;
        #pragma unroll
        for (int r = 0; r < 4; ++r){
          int grow = rbase + r;
          float v = acc[i][j][r] + cb;
          if (rowAdd) v += rowAdd[grow];
          v *= alpha;
          size_t idx = (size_t)grow * N + gcol;
          if (Cf) Cf[idx] = v;
          if (Chi){
            u16 hs = f2bf(v);
            Chi[idx] = hs;
            Clo[idx] = f2bf(v - bf2f(hs));
          }
        }
      }
    }
  }
}

extern "C" void kernel_launch(void* const* d_in, const int* in_sizes, int n_in,
                              void* d_out, int out_size, void* d_ws, size_t ws_size,
                              hipStream_t stream){
  (void)in_sizes; (void)n_in; (void)out_size; (void)ws_size;
  const float* m    = (const float*)d_in[0];   // [512][2048]
  const float* tpl  = (const float*)d_in[1];   // [50000][2048]
  const float* Wmol = (const float*)d_in[2];   // [1024][2048]
  const float* bmol = (const float*)d_in[3];   // [1024]
  const float* Wtmp = (const float*)d_in[4];   // [1024][2048]
  const float* btmp = (const float*)d_in[5];   // [1024]
  float* out = (float*)d_out;                  // [512][50000]

  uint8_t* wp = (uint8_t*)d_ws;
  auto carve = [&](size_t bytes) -> void* {
    void* p = (void*)wp;
    wp += (bytes + 255) & ~(size_t)255;
    return p;
  };
  u16* m_hi   = (u16*)carve((size_t)BB_ * FP_ * 2);
  u16* m_lo   = (u16*)carve((size_t)BB_ * FP_ * 2);
  u16* wm_hi  = (u16*)carve((size_t)AD_ * FP_ * 2);
  u16* wm_lo  = (u16*)carve((size_t)AD_ * FP_ * 2);
  u16* wtT_hi = (u16*)carve((size_t)FP_ * AD_ * 2);
  u16* wtT_lo = (u16*)carve((size_t)FP_ * AD_ * 2);
  float* Xi   = (float*)carve((size_t)BB_ * AD_ * 4);
  u16* Xi_hi  = (u16*)carve((size_t)BB_ * AD_ * 2);
  u16* Xi_lo  = (u16*)carve((size_t)BB_ * AD_ * 2);
  u16* Y_hi   = (u16*)carve((size_t)BB_ * FP_ * 2);
  u16* Y_lo   = (u16*)carve((size_t)BB_ * FP_ * 2);
  float* cvec = (float*)carve((size_t)BB_ * 4);

  // 1) split small operands to bf16 hi/lo (W_temp also transposed to [FP][A])
  conv_hilo_k<<<(BB_ * FP_ / 4 + 255) / 256, 256, 0, stream>>>(m, m_hi, m_lo, BB_ * FP_);
  conv_hilo_k<<<(AD_ * FP_ / 4 + 255) / 256, 256, 0, stream>>>(Wmol, wm_hi, wm_lo, AD_ * FP_);
  conv_hilo_T_k<<<dim3(FP_ / 32, AD_ / 32), dim3(32, 8), 0, stream>>>(Wtmp, wtT_hi, wtT_lo, AD_, FP_);

  // 2) Xi = m @ W_mol^T + b_mol   [512 x 1024], K=2048
  gemm_hilo<64, 64, 2, 2, false><<<dim3(BB_ / 64, AD_ / 64), 256, 0, stream>>>(
      m_hi, m_lo, wm_hi, wm_lo, nullptr, BB_, AD_, FP_,
      Xi, Xi_hi, Xi_lo, bmol, nullptr, 1.0f);

  // 3) c[b] = Xi[b,:] . b_temp
  dot_rows_k<<<BB_ / 4, 256, 0, stream>>>(Xi, btmp, cvec, AD_);

  // 4) Y = Xi @ W_temp   [512 x 2048], K=1024  (B^T = W_temp transposed)
  gemm_hilo<64, 64, 2, 2, false><<<dim3(BB_ / 64, FP_ / 64), 256, 0, stream>>>(
      Xi_hi, Xi_lo, wtT_hi, wtT_lo, nullptr, BB_, FP_, AD_,
      nullptr, Y_hi, Y_lo, nullptr, nullptr, 1.0f);

  // 5) out = BETA * (Y @ templates^T + c)   [512 x 50000], K=2048
  gemm_hilo<128, 128, 4, 4, true><<<dim3(BB_ / 128, (TT_ + 127) / 128), 256, 0, stream>>>(
      Y_hi, Y_lo, nullptr, nullptr, tpl, BB_, TT_, FP_,
      out, nullptr, nullptr, nullptr, cvec, BETA_);
}

// Round 2
// 470.297 us; speedup vs baseline: 1.1164x; 1.1164x over previous
//
#include <hip/hip_runtime.h>
#include <cstdint>
#include <cstddef>

typedef __attribute__((ext_vector_type(8))) short short8;   // 8 x bf16 (4 VGPRs) MFMA frag
typedef __attribute__((ext_vector_type(4))) float f32x4;    // MFMA accumulator
typedef __attribute__((ext_vector_type(4))) unsigned short u16x4;
typedef unsigned short u16;

#define FP_  2048
#define AD_  1024
#define BB_  512
#define TT_  50000
#define BETA_ 0.125f

// ---------- fp32 -> bf16 (RNE) helpers ----------
__device__ __forceinline__ u16 f2bf(float x){
  uint32_t u = __builtin_bit_cast(uint32_t, x);
  u = (u + 0x7fffu + ((u >> 16) & 1u)) >> 16;
  return (u16)u;
}
__device__ __forceinline__ float bf2f(u16 h){
  uint32_t u = ((uint32_t)h) << 16;
  return __builtin_bit_cast(float, u);
}

// ---------- elementwise fp32 -> (hi,lo) bf16 ----------
__global__ void conv_hilo_k(const float* __restrict__ src, u16* __restrict__ hi,
                            u16* __restrict__ lo, int n){
  int i = (blockIdx.x * blockDim.x + threadIdx.x) * 4;
  if (i >= n) return;
  f32x4 v = *reinterpret_cast<const f32x4*>(src + i);
  u16x4 h, l;
  #pragma unroll
  for (int e = 0; e < 4; ++e){
    float x = v[e];
    u16 hs = f2bf(x);
    h[e] = hs;
    l[e] = f2bf(x - bf2f(hs));
  }
  *reinterpret_cast<u16x4*>(hi + i) = h;
  *reinterpret_cast<u16x4*>(lo + i) = l;
}

// ---------- W[R][C] -> out[C][R] with hi/lo split (LDS tile transpose) ----------
__global__ void conv_hilo_T_k(const float* __restrict__ W, u16* __restrict__ hiT,
                              u16* __restrict__ loT, int R, int C){
  __shared__ float tile[32][33];
  int c0 = blockIdx.x * 32;
  int r0 = blockIdx.y * 32;
  int tx = threadIdx.x;   // 0..31
  int ty = threadIdx.y;   // 0..7
  #pragma unroll
  for (int i = 0; i < 32; i += 8)
    tile[ty + i][tx] = W[(size_t)(r0 + ty + i) * C + c0 + tx];
  __syncthreads();
  #pragma unroll
  for (int i = 0; i < 32; i += 8){
    float x = tile[tx][ty + i];              // = W[r0+tx][c0+ty+i]
    u16 hs = f2bf(x);
    size_t o = (size_t)(c0 + ty + i) * R + r0 + tx;   // out[f][a]
    hiT[o] = hs;
    loT[o] = f2bf(x - bf2f(hs));
  }
}

// ---------- c[b] = dot(Xi[b,:], b_temp) : one wave per row ----------
__global__ void dot_rows_k(const float* __restrict__ Xi, const float* __restrict__ bt,
                           float* __restrict__ c, int K){
  int row  = blockIdx.x * 4 + (threadIdx.x >> 6);
  int lane = threadIdx.x & 63;
  float s = 0.f;
  for (int a = lane; a < K; a += 64) s += Xi[(size_t)row * K + a] * bt[a];
  #pragma unroll
  for (int off = 32; off; off >>= 1) s += __shfl_down(s, off);
  if (lane == 0) c[row] = s;
}

// ---------- split-bf16 GEMM: C = alpha*(A·B^T + colBias + rowAdd) ----------
// 2-phase pipelined (T3-lite + T14): double-buffered LDS, next tile's global
// loads issued before the MFMA cluster, ONE barrier per K-step.
// a·b approximated by ah·bh + ah·bl + al·bh (3 MFMAs), fp32 accumulate.
template<int TM, int TN, int FM, int FN, bool BF32, bool SWZ>
__global__ __launch_bounds__(256, 2)
void gemm_hilo(const u16* __restrict__ Ahi, const u16* __restrict__ Alo,
               const u16* __restrict__ Bhi, const u16* __restrict__ Blo,
               const float* __restrict__ Bf,
               int M, int N, int K,
               float* __restrict__ Cf, u16* __restrict__ Chi, u16* __restrict__ Clo,
               const float* __restrict__ colBias, const float* __restrict__ rowAdd,
               float alpha)
{
  constexpr int BK = 32;
  constexpr int WM = TM / (16 * FM);
  constexpr int WN = TN / (16 * FN);
  static_assert(WM * WN == 4, "4 waves / 256 threads");
  constexpr int BUFE = (2 * TM + 2 * TN) * BK;   // u16 elems per buffer

  __shared__ u16 lds[2 * BUFE];

  int m0, n0;
  if constexpr (SWZ){
    // 1-D grid, 8*ceil(ntiles_n/8)*4 blocks. xcd = id%8 (HW round-robin);
    // all 4 M-tiles of an N-strip share the same residue -> same XCD L2.
    int id = blockIdx.x;
    int c  = id & 7;
    int k  = id >> 3;
    int mt = k & 3;          // M/TM == 4
    int nt = c + 8 * (k >> 2);
    m0 = mt * TM;
    n0 = nt * TN;
    if (n0 >= N) return;
  } else {
    m0 = blockIdx.x * TM;
    n0 = blockIdx.y * TN;
  }

  const int tid  = threadIdx.x;
  const int w    = tid >> 6;
  const int lane = tid & 63;
  const int lr   = lane & 15;   // fragment row index
  const int lg   = lane >> 4;   // k-chunk 0..3 (8 bf16 each)
  const int wm   = w / WN;
  const int wn   = w % WN;

  // staging-thread coords
  const int rrA = tid >> 2;     // 0..63 (A rows, bf16 path)
  const int chA = tid & 3;      // 16B chunk
  const int rrBf = tid >> 3;    // 0..31 (B rows, fp32 path)
  const int c4   = tid & 7;     // 4-float chunk

  // staged registers (next tile)
  short8 ra[TM / 64 > 0 ? TM / 64 : 1][2];
  f32x4  rbf[4];                // BF32: up to TN/32 = 4
  short8 rbb[TN / 64 > 0 ? TN / 64 : 1][2];

  f32x4 acc[FM][FN];
  #pragma unroll
  for (int i = 0; i < FM; ++i)
    #pragma unroll
    for (int j = 0; j < FN; ++j)
      acc[i][j] = (f32x4){0.f, 0.f, 0.f, 0.f};

  auto stage_load = [&](int k0){
    #pragma unroll
    for (int p = 0; p < TM / 64; ++p){
      int gm = m0 + rrA + p * 64;
      ra[p][0] = *reinterpret_cast<const short8*>(Ahi + (size_t)gm * K + k0 + chA * 8);
      ra[p][1] = *reinterpret_cast<const short8*>(Alo + (size_t)gm * K + k0 + chA * 8);
    }
    if constexpr (BF32){
      #pragma unroll
      for (int p = 0; p < TN / 32; ++p){
        int gn = n0 + rrBf + p * 32; if (gn > N - 1) gn = N - 1;
        rbf[p] = *reinterpret_cast<const f32x4*>(Bf + (size_t)gn * K + k0 + c4 * 4);
      }
    } else {
      #pragma unroll
      for (int p = 0; p < TN / 64; ++p){
        int gn = n0 + rrA + p * 64; if (gn > N - 1) gn = N - 1;
        rbb[p][0] = *reinterpret_cast<const short8*>(Bhi + (size_t)gn * K + k0 + chA * 8);
        rbb[p][1] = *reinterpret_cast<const short8*>(Blo + (size_t)gn * K + k0 + chA * 8);
      }
    }
  };

  auto stage_store = [&](int buf){
    u16* As_hi = lds + buf * BUFE;
    u16* As_lo = As_hi + TM * BK;
    u16* Bs_hi = As_hi + 2 * TM * BK;
    u16* Bs_lo = As_hi + 2 * TM * BK + TN * BK;
    #pragma unroll
    for (int p = 0; p < TM / 64; ++p){
      int row = rrA + p * 64;
      int sw  = (chA ^ ((row >> 1) & 3)) << 3;
      *reinterpret_cast<short8*>(As_hi + row * BK + sw) = ra[p][0];
      *reinterpret_cast<short8*>(As_lo + row * BK + sw) = ra[p][1];
    }
    if constexpr (BF32){
      #pragma unroll
      for (int p = 0; p < TN / 32; ++p){
        int row = rrBf + p * 32;
        u16x4 h, l;
        #pragma unroll
        for (int e = 0; e < 4; ++e){
          float x = rbf[p][e];
          uint32_t u = __builtin_bit_cast(uint32_t, x);
          u16 hs = (u16)(u >> 16);                                   // trunc hi
          float hf = __builtin_bit_cast(float, u & 0xffff0000u);
          h[e] = hs;
          l[e] = f2bf(x - hf);                                       // RNE lo
        }
        int off = row * BK + (((c4 >> 1) ^ ((row >> 1) & 3)) << 3) + (c4 & 1) * 4;
        *reinterpret_cast<u16x4*>(Bs_hi + off) = h;
        *reinterpret_cast<u16x4*>(Bs_lo + off) = l;
      }
    } else {
      #pragma unroll
      for (int p = 0; p < TN / 64; ++p){
        int row = rrA + p * 64;
        int sw  = (chA ^ ((row >> 1) & 3)) << 3;
        *reinterpret_cast<short8*>(Bs_hi + row * BK + sw) = rbb[p][0];
        *reinterpret_cast<short8*>(Bs_lo + row * BK + sw) = rbb[p][1];
      }
    }
  };

  const int NT = K / BK;
  stage_load(0);
  stage_store(0);
  __syncthreads();

  int cur = 0;
  for (int t = 0; t < NT; ++t){
    const bool have_next = (t + 1 < NT);
    if (have_next) stage_load((t + 1) * BK);   // VMEM in flight under MFMA

    u16* As_hi = lds + cur * BUFE;
    u16* As_lo = As_hi + TM * BK;
    u16* Bs_hi = As_hi + 2 * TM * BK;
    u16* Bs_lo = As_hi + 2 * TM * BK + TN * BK;

    short8 ah[FM], al[FM], bh[FN], bl[FN];
    #pragma unroll
    for (int i = 0; i < FM; ++i){
      int row = wm * FM * 16 + i * 16 + lr;
      int off = row * BK + ((lg ^ ((row >> 1) & 3)) << 3);
      ah[i] = *reinterpret_cast<short8*>(As_hi + off);
      al[i] = *reinterpret_cast<short8*>(As_lo + off);
    }
    #pragma unroll
    for (int j = 0; j < FN; ++j){
      int row = wn * FN * 16 + j * 16 + lr;
      int off = row * BK + ((lg ^ ((row >> 1) & 3)) << 3);
      bh[j] = *reinterpret_cast<short8*>(Bs_hi + off);
      bl[j] = *reinterpret_cast<short8*>(Bs_lo + off);
    }
    #pragma unroll
    for (int i = 0; i < FM; ++i)
      #pragma unroll
      for (int j = 0; j < FN; ++j){
        acc[i][j] = __builtin_amdgcn_mfma_f32_16x16x32_bf16(ah[i], bh[j], acc[i][j], 0, 0, 0);
        acc[i][j] = __builtin_amdgcn_mfma_f32_16x16x32_bf16(ah[i], bl[j], acc[i][j], 0, 0, 0);
        acc[i][j] = __builtin_amdgcn_mfma_f32_16x16x32_bf16(al[i], bh[j], acc[i][j], 0, 0, 0);
      }

    if (have_next){
      // Keep the convert/ds_write (which waits on the staged loads) from being
      // scheduled above the MFMA cluster — that would drag vmcnt(0) pre-MFMA.
      __builtin_amdgcn_sched_barrier(0);
      stage_store(cur ^ 1);
      __syncthreads();               // writes visible; prior reads of cur done
    }
    cur ^= 1;
  }

  // ---- epilogue: C[row= A index][col= B index]; row=(lane>>4)*4+reg, col=lane&15 ----
  #pragma unroll
  for (int i = 0; i < FM; ++i){
    int rbase = m0 + wm * FM * 16 + i * 16 + lg * 4;
    #pragma unroll
    for (int j = 0; j < FN; ++j){
      int gcol = n0 + wn * FN * 16 + j * 16 + lr;
      if (gcol < N){
        float cb = colBias ? colBias[gcol] : 0.f;
        #pragma unroll
        for (int r = 0; r < 4; ++r){
          int grow = rbase + r;
          float v = acc[i][j][r] + cb;
          if (rowAdd) v += rowAdd[grow];
          v *= alpha;
          size_t idx = (size_t)grow * N + gcol;
          if (Cf) Cf[idx] = v;
          if (Chi){
            u16 hs = f2bf(v);
            Chi[idx] = hs;
            Clo[idx] = f2bf(v - bf2f(hs));
          }
        }
      }
    }
  }
}

extern "C" void kernel_launch(void* const* d_in, const int* in_sizes, int n_in,
                              void* d_out, int out_size, void* d_ws, size_t ws_size,
                              hipStream_t stream){
  (void)in_sizes; (void)n_in; (void)out_size; (void)ws_size;
  const float* m    = (const float*)d_in[0];   // [512][2048]
  const float* tpl  = (const float*)d_in[1];   // [50000][2048]
  const float* Wmol = (const float*)d_in[2];   // [1024][2048]
  const float* bmol = (const float*)d_in[3];   // [1024]
  const float* Wtmp = (const float*)d_in[4];   // [1024][2048]
  const float* btmp = (const float*)d_in[5];   // [1024]
  float* out = (float*)d_out;                  // [512][50000]

  uint8_t* wp = (uint8_t*)d_ws;
  auto carve = [&](size_t bytes) -> void* {
    void* p = (void*)wp;
    wp += (bytes + 255) & ~(size_t)255;
    return p;
  };
  u16* m_hi   = (u16*)carve((size_t)BB_ * FP_ * 2);
  u16* m_lo   = (u16*)carve((size_t)BB_ * FP_ * 2);
  u16* wm_hi  = (u16*)carve((size_t)AD_ * FP_ * 2);
  u16* wm_lo  = (u16*)carve((size_t)AD_ * FP_ * 2);
  u16* wtT_hi = (u16*)carve((size_t)FP_ * AD_ * 2);
  u16* wtT_lo = (u16*)carve((size_t)FP_ * AD_ * 2);
  float* Xi   = (float*)carve((size_t)BB_ * AD_ * 4);
  u16* Xi_hi  = (u16*)carve((size_t)BB_ * AD_ * 2);
  u16* Xi_lo  = (u16*)carve((size_t)BB_ * AD_ * 2);
  u16* Y_hi   = (u16*)carve((size_t)BB_ * FP_ * 2);
  u16* Y_lo   = (u16*)carve((size_t)BB_ * FP_ * 2);
  float* cvec = (float*)carve((size_t)BB_ * 4);

  // 1) split small operands to bf16 hi/lo (W_temp also transposed to [FP][A])
  conv_hilo_k<<<(BB_ * FP_ / 4 + 255) / 256, 256, 0, stream>>>(m, m_hi, m_lo, BB_ * FP_);
  conv_hilo_k<<<(AD_ * FP_ / 4 + 255) / 256, 256, 0, stream>>>(Wmol, wm_hi, wm_lo, AD_ * FP_);
  conv_hilo_T_k<<<dim3(FP_ / 32, AD_ / 32), dim3(32, 8), 0, stream>>>(Wtmp, wtT_hi, wtT_lo, AD_, FP_);

  // 2) Xi = m @ W_mol^T + b_mol   [512 x 1024], K=2048
  gemm_hilo<64, 64, 2, 2, false, false><<<dim3(BB_ / 64, AD_ / 64), 256, 0, stream>>>(
      m_hi, m_lo, wm_hi, wm_lo, nullptr, BB_, AD_, FP_,
      Xi, Xi_hi, Xi_lo, bmol, nullptr, 1.0f);

  // 3) c[b] = Xi[b,:] . b_temp
  dot_rows_k<<<BB_ / 4, 256, 0, stream>>>(Xi, btmp, cvec, AD_);

  // 4) Y = Xi @ W_temp   [512 x 2048], K=1024  (B^T = W_temp transposed)
  gemm_hilo<64, 64, 2, 2, false, false><<<dim3(BB_ / 64, FP_ / 64), 256, 0, stream>>>(
      Xi_hi, Xi_lo, wtT_hi, wtT_lo, nullptr, BB_, FP_, AD_,
      nullptr, Y_hi, Y_lo, nullptr, nullptr, 1.0f);

  // 5) out = BETA * (Y @ templates^T + c)   [512 x 50000], K=2048
  //    1-D XCD-grouped grid: 8 residues * ceil(391/8) groups * 4 M-tiles
  {
    int ntiles_n = (TT_ + 127) / 128;            // 391
    int grid = 8 * ((ntiles_n + 7) / 8) * 4;     // 1568 (4 masked tail blocks)
    gemm_hilo<128, 128, 4, 4, true, true><<<grid, 256, 0, stream>>>(
        Y_hi, Y_lo, nullptr, nullptr, tpl, BB_, TT_, FP_,
        out, nullptr, nullptr, nullptr, cvec, BETA_);
  }
}

// Round 3
// 366.267 us; speedup vs baseline: 1.4335x; 1.2840x over previous
//
#include <hip/hip_runtime.h>
#include <cstdint>
#include <cstddef>

typedef __attribute__((ext_vector_type(8))) short short8;     // 8 x 16-bit (4 VGPRs)
typedef __attribute__((ext_vector_type(8))) _Float16 f16x8;   // fp16 MFMA frag
typedef __attribute__((ext_vector_type(4))) float f32x4;
typedef __attribute__((ext_vector_type(4))) unsigned short u16x4;
typedef unsigned short u16;

#define FP_  2048
#define AD_  1024
#define BB_  512
#define TT_  50000
#define BETA_ 0.125f

// ---------- fp32 -> bf16 (RNE) helpers ----------
__device__ __forceinline__ u16 f2bf(float x){
  uint32_t u = __builtin_bit_cast(uint32_t, x);
  u = (u + 0x7fffu + ((u >> 16) & 1u)) >> 16;
  return (u16)u;
}
__device__ __forceinline__ float bf2f(u16 h){
  uint32_t u = ((uint32_t)h) << 16;
  return __builtin_bit_cast(float, u);
}
__device__ __forceinline__ u16 f2h_bits(float x){
  _Float16 h = (_Float16)x;            // RNE
  return __builtin_bit_cast(u16, h);
}

// ---------- async global->LDS, 16B per lane ----------
__device__ __forceinline__ void gload_lds16(const void* g, void* l){
  __builtin_amdgcn_global_load_lds((const __attribute__((address_space(1))) void*)g,
                                   (__attribute__((address_space(3))) void*)l,
                                   16, 0, 0);
}

// ---------- elementwise fp32 -> (hi,lo) bf16 ----------
__global__ void conv_hilo_k(const float* __restrict__ src, u16* __restrict__ hi,
                            u16* __restrict__ lo, int n){
  int i = (blockIdx.x * blockDim.x + threadIdx.x) * 4;
  if (i >= n) return;
  f32x4 v = *reinterpret_cast<const f32x4*>(src + i);
  u16x4 h, l;
  #pragma unroll
  for (int e = 0; e < 4; ++e){
    float x = v[e];
    u16 hs = f2bf(x);
    h[e] = hs;
    l[e] = f2bf(x - bf2f(hs));
  }
  *reinterpret_cast<u16x4*>(hi + i) = h;
  *reinterpret_cast<u16x4*>(lo + i) = l;
}

// ---------- W[R][C] -> out[C][R] with hi/lo split (LDS tile transpose) ----------
__global__ void conv_hilo_T_k(const float* __restrict__ W, u16* __restrict__ hiT,
                              u16* __restrict__ loT, int R, int C){
  __shared__ float tile[32][33];
  int c0 = blockIdx.x * 32;
  int r0 = blockIdx.y * 32;
  int tx = threadIdx.x;   // 0..31
  int ty = threadIdx.y;   // 0..7
  #pragma unroll
  for (int i = 0; i < 32; i += 8)
    tile[ty + i][tx] = W[(size_t)(r0 + ty + i) * C + c0 + tx];
  __syncthreads();
  #pragma unroll
  for (int i = 0; i < 32; i += 8){
    float x = tile[tx][ty + i];              // = W[r0+tx][c0+ty+i]
    u16 hs = f2bf(x);
    size_t o = (size_t)(c0 + ty + i) * R + r0 + tx;   // out[f][a]
    hiT[o] = hs;
    loT[o] = f2bf(x - bf2f(hs));
  }
}

// ---------- c[b] = dot(Xi[b,:], b_temp) : one wave per row ----------
__global__ void dot_rows_k(const float* __restrict__ Xi, const float* __restrict__ bt,
                           float* __restrict__ c, int K){
  int row  = blockIdx.x * 4 + (threadIdx.x >> 6);
  int lane = threadIdx.x & 63;
  float s = 0.f;
  for (int a = lane; a < K; a += 64) s += Xi[(size_t)row * K + a] * bt[a];
  #pragma unroll
  for (int off = 32; off; off >>= 1) s += __shfl_down(s, off);
  if (lane == 0) c[row] = s;
}

// ---------- split-bf16 small GEMM: C = A·B^T + colBias (3-term hi/lo) ----------
// OUT16: 0=none, 1=bf16 hi/lo pair, 2=fp16 hi/lo pair
template<int TM, int TN, int FM, int FN, int OUT16>
__global__ __launch_bounds__(256, 2)
void gemm_hilo(const u16* __restrict__ Ahi, const u16* __restrict__ Alo,
               const u16* __restrict__ Bhi, const u16* __restrict__ Blo,
               int M, int N, int K,
               float* __restrict__ Cf, u16* __restrict__ Chi, u16* __restrict__ Clo,
               const float* __restrict__ colBias)
{
  constexpr int BK = 32;
  constexpr int WM = TM / (16 * FM);
  constexpr int WN = TN / (16 * FN);
  static_assert(WM * WN == 4, "4 waves / 256 threads");
  constexpr int BUFE = (2 * TM + 2 * TN) * BK;

  __shared__ __align__(16) u16 lds[2 * BUFE];

  const int m0 = blockIdx.x * TM;
  const int n0 = blockIdx.y * TN;

  const int tid  = threadIdx.x;
  const int w    = tid >> 6;
  const int lane = tid & 63;
  const int lr   = lane & 15;
  const int lg   = lane >> 4;
  const int wm   = w / WN;
  const int wn   = w % WN;

  const int rrA = tid >> 2;     // 0..63
  const int chA = tid & 3;      // 16B chunk

  short8 ra[2], rb[2];

  f32x4 acc[FM][FN];
  #pragma unroll
  for (int i = 0; i < FM; ++i)
    #pragma unroll
    for (int j = 0; j < FN; ++j)
      acc[i][j] = (f32x4){0.f, 0.f, 0.f, 0.f};

  auto stage_load = [&](int k0){
    int gm = m0 + rrA;
    ra[0] = *reinterpret_cast<const short8*>(Ahi + (size_t)gm * K + k0 + chA * 8);
    ra[1] = *reinterpret_cast<const short8*>(Alo + (size_t)gm * K + k0 + chA * 8);
    int gn = n0 + rrA; if (gn > N - 1) gn = N - 1;
    rb[0] = *reinterpret_cast<const short8*>(Bhi + (size_t)gn * K + k0 + chA * 8);
    rb[1] = *reinterpret_cast<const short8*>(Blo + (size_t)gn * K + k0 + chA * 8);
  };
  auto stage_store = [&](int buf){
    u16* As_hi = lds + buf * BUFE;
    u16* As_lo = As_hi + TM * BK;
    u16* Bs_hi = As_hi + 2 * TM * BK;
    u16* Bs_lo = As_hi + 2 * TM * BK + TN * BK;
    int row = rrA;
    int sw  = (chA ^ ((row >> 1) & 3)) << 3;
    *reinterpret_cast<short8*>(As_hi + row * BK + sw) = ra[0];
    *reinterpret_cast<short8*>(As_lo + row * BK + sw) = ra[1];
    *reinterpret_cast<short8*>(Bs_hi + row * BK + sw) = rb[0];
    *reinterpret_cast<short8*>(Bs_lo + row * BK + sw) = rb[1];
  };

  const int NT = K / BK;
  stage_load(0);
  stage_store(0);
  __syncthreads();

  int cur = 0;
  for (int t = 0; t < NT; ++t){
    const bool have_next = (t + 1 < NT);
    if (have_next) stage_load((t + 1) * BK);

    u16* As_hi = lds + cur * BUFE;
    u16* As_lo = As_hi + TM * BK;
    u16* Bs_hi = As_hi + 2 * TM * BK;
    u16* Bs_lo = As_hi + 2 * TM * BK + TN * BK;

    short8 ah[FM], al[FM], bh[FN], bl[FN];
    #pragma unroll
    for (int i = 0; i < FM; ++i){
      int row = wm * FM * 16 + i * 16 + lr;
      int off = row * BK + ((lg ^ ((row >> 1) & 3)) << 3);
      ah[i] = *reinterpret_cast<short8*>(As_hi + off);
      al[i] = *reinterpret_cast<short8*>(As_lo + off);
    }
    #pragma unroll
    for (int j = 0; j < FN; ++j){
      int row = wn * FN * 16 + j * 16 + lr;
      int off = row * BK + ((lg ^ ((row >> 1) & 3)) << 3);
      bh[j] = *reinterpret_cast<short8*>(Bs_hi + off);
      bl[j] = *reinterpret_cast<short8*>(Bs_lo + off);
    }
    #pragma unroll
    for (int i = 0; i < FM; ++i)
      #pragma unroll
      for (int j = 0; j < FN; ++j){
        acc[i][j] = __builtin_amdgcn_mfma_f32_16x16x32_bf16(ah[i], bh[j], acc[i][j], 0, 0, 0);
        acc[i][j] = __builtin_amdgcn_mfma_f32_16x16x32_bf16(ah[i], bl[j], acc[i][j], 0, 0, 0);
        acc[i][j] = __builtin_amdgcn_mfma_f32_16x16x32_bf16(al[i], bh[j], acc[i][j], 0, 0, 0);
      }

    if (have_next){
      __builtin_amdgcn_sched_barrier(0);
      stage_store(cur ^ 1);
      __syncthreads();
    }
    cur ^= 1;
  }

  #pragma unroll
  for (int i = 0; i < FM; ++i){
    int rbase = m0 + wm * FM * 16 + i * 16 + lg * 4;
    #pragma unroll
    for (int j = 0; j < FN; ++j){
      int gcol = n0 + wn * FN * 16 + j * 16 + lr;
      if (gcol < N){
        float cb = colBias ? colBias[gcol] : 0.f;
        #pragma unroll
        for (int r = 0; r < 4; ++r){
          int grow = rbase + r;
          float v = acc[i][j][r] + cb;
          size_t idx = (size_t)grow * N + gcol;
          if (Cf) Cf[idx] = v;
          if constexpr (OUT16 == 1){
            u16 hs = f2bf(v);
            Chi[idx] = hs;
            Clo[idx] = f2bf(v - bf2f(hs));
          } else if constexpr (OUT16 == 2){
            _Float16 h = (_Float16)v;
            Chi[idx] = __builtin_bit_cast(u16, h);
            Clo[idx] = f2h_bits(v - (float)h);
          }
        }
      }
    }
  }
}

// ---------- BIG GEMM: out = alpha*(A·B^T + rowAdd), A = fp16 hi/lo (2-term), ----------
// ---------- B = fp32 converted to fp16 in staging. 128x128 tile, BK=32.     ----------
__global__ __launch_bounds__(256, 3)
void gemm_big(const u16* __restrict__ Ah, const u16* __restrict__ Al,  // fp16 bits [512][2048]
              const float* __restrict__ Bf,                            // [50000][2048]
              float* __restrict__ C,
              const float* __restrict__ rowAdd, float alpha)
{
  constexpr int TM = 128, TN = 128, BK = 32;
  constexpr int K = FP_, N = TT_;
  constexpr int NTN = (TT_ + TN - 1) / TN;    // 391
  constexpr int ABUF = TM * BK;               // 4096 u16 = 8 KB
  constexpr int BUFE = 3 * ABUF;              // Ah, Al, B

  __shared__ __align__(16) u16 lds[2 * BUFE]; // 48 KB

  // XCD-grouped 1-D grid: id = c + 8*(mt + 4*g), nt = c + 8*g
  int id = blockIdx.x;
  int c  = id & 7;
  int k  = id >> 3;
  int mt = k & 3;
  int nt = c + 8 * (k >> 2);
  if (nt >= NTN) return;
  const int m0 = mt * TM;
  const int n0 = nt * TN;

  const int tid  = threadIdx.x;
  const int w    = tid >> 6;
  const int lane = tid & 63;
  const int lr   = lane & 15;
  const int lg   = lane >> 4;
  const int wm   = w >> 1;      // 2x2 wave grid, wave tile 64x64
  const int wn   = w & 1;

  const int rrB = tid >> 3;     // 0..31
  const int c4  = tid & 7;      // 4-float chunk

  f32x4 rbf[4];

  auto loadB = [&](int k0){
    #pragma unroll
    for (int p = 0; p < 4; ++p){
      int gn = n0 + rrB + p * 32; if (gn > N - 1) gn = N - 1;
      rbf[p] = *reinterpret_cast<const f32x4*>(Bf + (size_t)gn * K + k0 + c4 * 4);
    }
  };
  // async A stage: per wave 4x global_load_lds (hi/lo x 2 row-groups of 16).
  // LDS dest is lane-linear (base + lane*16B); source address carries the
  // inverse chunk-swizzle so that ds_read with the same swizzle is conflict-free.
  auto ldsA = [&](int k0, int buf){
    const int rloc = lane >> 2;        // 0..15
    const int cc   = lane & 3;         // 16B chunk
    #pragma unroll
    for (int arr = 0; arr < 2; ++arr){
      const u16* src = arr ? Al : Ah;
      u16* dstbase = lds + buf * BUFE + arr * ABUF;
      #pragma unroll
      for (int q = 0; q < 2; ++q){
        int row = w * 32 + q * 16 + rloc;
        int sc  = cc ^ ((row >> 1) & 3);
        const void* g = src + (size_t)(m0 + row) * K + k0 + sc * 8;
        gload_lds16(g, dstbase + (size_t)(w * 32 + q * 16) * BK);
      }
    }
  };
  auto storeB = [&](int buf){
    u16* Bbase = lds + buf * BUFE + 2 * ABUF;
    #pragma unroll
    for (int p = 0; p < 4; ++p){
      int row = rrB + p * 32;
      u16x4 hv;
      #pragma unroll
      for (int e = 0; e < 4; ++e) hv[e] = f2h_bits(rbf[p][e]);
      int cc2 = c4 >> 1;
      int off = row * BK + ((cc2 ^ ((row >> 1) & 3)) << 3) + (c4 & 1) * 4;
      *reinterpret_cast<u16x4*>(Bbase + off) = hv;
    }
  };

  f32x4 acc[4][4];
  #pragma unroll
  for (int i = 0; i < 4; ++i)
    #pragma unroll
    for (int j = 0; j < 4; ++j)
      acc[i][j] = (f32x4){0.f, 0.f, 0.f, 0.f};

  // prologue
  loadB(0);
  ldsA(0, 0);
  storeB(0);
  __syncthreads();    // drains vmcnt(0): gload_lds + B loads

  constexpr int NT = K / BK;   // 64
  int cur = 0;
  for (int t = 0; t < NT; ++t){
    const bool have_next = (t + 1 < NT);
    if (have_next){
      loadB((t + 1) * BK);          // B first (waited mid-step by convert)
      ldsA((t + 1) * BK, cur ^ 1);  // A-lds stays in flight until syncthreads
    }

    u16* Abase = lds + cur * BUFE;
    f16x8 a0[4], a1[4], b[4];
    #pragma unroll
    for (int i = 0; i < 4; ++i){
      int row = wm * 64 + i * 16 + lr;
      int off = row * BK + ((lg ^ ((row >> 1) & 3)) << 3);
      a0[i] = __builtin_bit_cast(f16x8, *reinterpret_cast<short8*>(Abase + off));
      a1[i] = __builtin_bit_cast(f16x8, *reinterpret_cast<short8*>(Abase + ABUF + off));
    }
    #pragma unroll
    for (int j = 0; j < 4; ++j){
      int row = wn * 64 + j * 16 + lr;
      int off = row * BK + ((lg ^ ((row >> 1) & 3)) << 3);
      b[j] = __builtin_bit_cast(f16x8, *reinterpret_cast<short8*>(Abase + 2 * ABUF + off));
    }
    #pragma unroll
    for (int i = 0; i < 4; ++i)
      #pragma unroll
      for (int j = 0; j < 4; ++j){
        acc[i][j] = __builtin_amdgcn_mfma_f32_16x16x32_f16(a0[i], b[j], acc[i][j], 0, 0, 0);
        acc[i][j] = __builtin_amdgcn_mfma_f32_16x16x32_f16(a1[i], b[j], acc[i][j], 0, 0, 0);
      }

    if (have_next){
      __builtin_amdgcn_sched_barrier(0);  // keep convert's vmcnt wait below MFMAs
      storeB(cur ^ 1);
      __syncthreads();
    }
    cur ^= 1;
  }

  // epilogue: row=(lane>>4)*4+reg (A index), col=lane&15 (B index)
  #pragma unroll
  for (int i = 0; i < 4; ++i){
    int rbase = m0 + wm * 64 + i * 16 + lg * 4;
    #pragma unroll
    for (int j = 0; j < 4; ++j){
      int gcol = n0 + wn * 64 + j * 16 + lr;
      if (gcol < N){
        #pragma unroll
        for (int r = 0; r < 4; ++r){
          int grow = rbase + r;
          float v = (acc[i][j][r] + rowAdd[grow]) * alpha;
          C[(size_t)grow * N + gcol] = v;
        }
      }
    }
  }
}

extern "C" void kernel_launch(void* const* d_in, const int* in_sizes, int n_in,
                              void* d_out, int out_size, void* d_ws, size_t ws_size,
                              hipStream_t stream){
  (void)in_sizes; (void)n_in; (void)out_size; (void)ws_size;
  const float* m    = (const float*)d_in[0];   // [512][2048]
  const float* tpl  = (const float*)d_in[1];   // [50000][2048]
  const float* Wmol = (const float*)d_in[2];   // [1024][2048]
  const float* bmol = (const float*)d_in[3];   // [1024]
  const float* Wtmp = (const float*)d_in[4];   // [1024][2048]
  const float* btmp = (const float*)d_in[5];   // [1024]
  float* out = (float*)d_out;                  // [512][50000]

  uint8_t* wp = (uint8_t*)d_ws;
  auto carve = [&](size_t bytes) -> void* {
    void* p = (void*)wp;
    wp += (bytes + 255) & ~(size_t)255;
    return p;
  };
  u16* m_hi   = (u16*)carve((size_t)BB_ * FP_ * 2);
  u16* m_lo   = (u16*)carve((size_t)BB_ * FP_ * 2);
  u16* wm_hi  = (u16*)carve((size_t)AD_ * FP_ * 2);
  u16* wm_lo  = (u16*)carve((size_t)AD_ * FP_ * 2);
  u16* wtT_hi = (u16*)carve((size_t)FP_ * AD_ * 2);
  u16* wtT_lo = (u16*)carve((size_t)FP_ * AD_ * 2);
  float* Xi   = (float*)carve((size_t)BB_ * AD_ * 4);
  u16* Xi_hi  = (u16*)carve((size_t)BB_ * AD_ * 2);
  u16* Xi_lo  = (u16*)carve((size_t)BB_ * AD_ * 2);
  u16* Y_hi   = (u16*)carve((size_t)BB_ * FP_ * 2);   // fp16 bits
  u16* Y_lo   = (u16*)carve((size_t)BB_ * FP_ * 2);   // fp16 bits
  float* cvec = (float*)carve((size_t)BB_ * 4);

  // 1) split inputs to bf16 hi/lo (W_temp also transposed to [FP][A])
  conv_hilo_k<<<(BB_ * FP_ / 4 + 255) / 256, 256, 0, stream>>>(m, m_hi, m_lo, BB_ * FP_);
  conv_hilo_k<<<(AD_ * FP_ / 4 + 255) / 256, 256, 0, stream>>>(Wmol, wm_hi, wm_lo, AD_ * FP_);
  conv_hilo_T_k<<<dim3(FP_ / 32, AD_ / 32), dim3(32, 8), 0, stream>>>(Wtmp, wtT_hi, wtT_lo, AD_, FP_);

  // 2) Xi = m @ W_mol^T + b_mol   [512 x 1024], K=2048  (fp32 + bf16 hi/lo out)
  gemm_hilo<64, 64, 2, 2, 1><<<dim3(BB_ / 64, AD_ / 64), 256, 0, stream>>>(
      m_hi, m_lo, wm_hi, wm_lo, BB_, AD_, FP_,
      Xi, Xi_hi, Xi_lo, bmol);

  // 3) c[b] = Xi[b,:] . b_temp
  dot_rows_k<<<BB_ / 4, 256, 0, stream>>>(Xi, btmp, cvec, AD_);

  // 4) Y = Xi @ W_temp   [512 x 2048], K=1024  -> fp16 hi/lo
  gemm_hilo<64, 64, 2, 2, 2><<<dim3(BB_ / 64, FP_ / 64), 256, 0, stream>>>(
      Xi_hi, Xi_lo, wtT_hi, wtT_lo, BB_, FP_, AD_,
      nullptr, Y_hi, Y_lo, nullptr);

  // 5) out = BETA * (Y @ templates^T + c)   [512 x 50000], K=2048
  {
    constexpr int ntn = (TT_ + 127) / 128;          // 391
    int grid = 8 * ((ntn + 7) / 8) * 4;             // 1568
    gemm_big<<<grid, 256, 0, stream>>>(Y_hi, Y_lo, tpl, out, cvec, BETA_);
  }
}